// Round 1
// baseline (689.319 us; speedup 1.0000x reference)
//
#include <hip/hip_runtime.h>
#include <hip/hip_bf16.h>

typedef unsigned short u16;
typedef __bf16 bf16x8 __attribute__((ext_vector_type(8)));
typedef float f32x4 __attribute__((ext_vector_type(4)));

#define DEVI __device__ __forceinline__

DEVI u16 f2bf(float f) {
    unsigned u = __builtin_bit_cast(unsigned, f);
    u += 0x7fff + ((u >> 16) & 1);   // RNE; inputs are finite
    return (u16)(u >> 16);
}
DEVI float bf2f(u16 h) {
    unsigned u = ((unsigned)h) << 16;
    return __builtin_bit_cast(float, u);
}

typedef __attribute__((address_space(1))) const unsigned GU32;
typedef __attribute__((address_space(3))) unsigned LU32;

DEVI void gload_lds16(const void* g, void* l) {
    __builtin_amdgcn_global_load_lds((GU32*)g, (LU32*)l, 16, 0, 0);
}

// ---------------------------------------------------------------------------
// Shared mainloop: C[128x128] += A[M x K] * B^T  (B stored N x K row-major).
// 256 threads = 4 waves in 2x2; each wave owns a 64x64 quadrant as 4x4
// fragments of 16x16x32 bf16 MFMA. BK=64, single-buffered LDS,
// global_load_lds width-16 staging (m97 structure).
// ---------------------------------------------------------------------------
DEVI void gemm_mainloop(const u16* __restrict__ A, int lda,
                        const u16* __restrict__ B, int ldb,
                        int K, int m0, int n0,
                        u16* lA, u16* lB, f32x4 acc[4][4])
{
    const int tid  = threadIdx.x;
    const int wave = tid >> 6, lane = tid & 63;
    const int lr = lane & 15, lq = lane >> 4;
    const int wm = (wave >> 1) * 64, wn = (wave & 1) * 64;

    for (int k0 = 0; k0 < K; k0 += 64) {
        // Stage 128x64 bf16 tiles (16KB each): 16 chunks of 1KB (64 lanes x 16B).
        #pragma unroll
        for (int c = 0; c < 4; ++c) {
            int chunk = c * 4 + wave;          // wave-uniform
            int e   = chunk * 512 + lane * 8;  // element offset in tile
            int row = e >> 6, kk = e & 63;
            gload_lds16(A + (size_t)(m0 + row) * lda + k0 + kk, lA + chunk * 512);
            gload_lds16(B + (size_t)(n0 + row) * ldb + k0 + kk, lB + chunk * 512);
        }
        asm volatile("s_waitcnt vmcnt(0)" ::: "memory");
        __syncthreads();

        #pragma unroll
        for (int kk = 0; kk < 64; kk += 32) {
            bf16x8 av[4], bv[4];
            #pragma unroll
            for (int i = 0; i < 4; ++i)
                av[i] = *(const bf16x8*)(lA + (wm + i * 16 + lr) * 64 + kk + lq * 8);
            #pragma unroll
            for (int j = 0; j < 4; ++j)
                bv[j] = *(const bf16x8*)(lB + (wn + j * 16 + lr) * 64 + kk + lq * 8);
            #pragma unroll
            for (int i = 0; i < 4; ++i)
                #pragma unroll
                for (int j = 0; j < 4; ++j)
                    acc[i][j] = __builtin_amdgcn_mfma_f32_16x16x32_bf16(av[i], bv[j], acc[i][j], 0, 0, 0);
        }
        __syncthreads();
    }
}

// Output coords: row = m0+wm+i*16+lq*4+rr, col = n0+wn+j*16+lr  (C/D layout m89-verified)
#define EPILOGUE_COORDS()                                   \
    const int tid  = threadIdx.x;                           \
    const int wave = tid >> 6, lane = tid & 63;             \
    const int lr = lane & 15, lq = lane >> 4;               \
    const int wm = (wave >> 1) * 64, wn = (wave & 1) * 64;  \
    (void)tid;

// ---------------------------------------------------------------------------
// Prep kernels
// ---------------------------------------------------------------------------
__global__ __launch_bounds__(256) void k_cast_x(const float* __restrict__ x, u16* __restrict__ xb)
{
    size_t i = (size_t)blockIdx.x * 256 + threadIdx.x;   // one float4 per thread
    float4 f = ((const float4*)x)[i];
    ushort4 o;
    o.x = f2bf(f.x); o.y = f2bf(f.y); o.z = f2bf(f.z); o.w = f2bf(f.w);
    ((ushort4*)xb)[i] = o;
}

// in: R x C f32 row-major  ->  out: C x R bf16 row-major
__global__ void k_transpose_w(const float* __restrict__ in, u16* __restrict__ out, int R, int C)
{
    __shared__ u16 t[32][33];
    int c0 = blockIdx.x * 32, r0 = blockIdx.y * 32;
    int tx = threadIdx.x, ty = threadIdx.y;
    #pragma unroll
    for (int p = 0; p < 4; ++p) {
        int rr = ty + p * 8;
        t[rr][tx] = f2bf(in[(size_t)(r0 + rr) * C + c0 + tx]);
    }
    __syncthreads();
    #pragma unroll
    for (int p = 0; p < 4; ++p) {
        int cc = ty + p * 8;
        out[(size_t)(c0 + cc) * R + r0 + tx] = t[tx][cc];
    }
}

// v [B*4096 x 1536] bf16 -> vT [B][1536][4096] bf16
__global__ __launch_bounds__(256) void k_transpose_v(const u16* __restrict__ v, u16* __restrict__ vT)
{
    __shared__ u16 t[64][72];
    int b = blockIdx.z;
    int n0 = blockIdx.x * 64, d0 = blockIdx.y * 64;
    int tid = threadIdx.x;
    #pragma unroll
    for (int p = 0; p < 2; ++p) {
        int row = (tid >> 3) + p * 32;        // n
        int cg  = (tid & 7) * 8;              // d
        uint4 w = *(const uint4*)(v + (size_t)(b * 4096 + n0 + row) * 1536 + d0 + cg);
        *(uint4*)&t[row][cg] = w;
    }
    __syncthreads();
    #pragma unroll
    for (int p = 0; p < 2; ++p) {
        int dr = (tid >> 3) + p * 32;         // d
        int nc = (tid & 7) * 8;               // n
        u16 tmp[8];
        #pragma unroll
        for (int e = 0; e < 8; ++e) tmp[e] = t[nc + e][dr];
        *(uint4*)(vT + (size_t)b * 1536 * 4096 + (size_t)(d0 + dr) * 4096 + n0 + nc) = *(const uint4*)tmp;
    }
}

// ---------------------------------------------------------------------------
// GEMM1: h = silu(x@Wi + bi); split -> u, v (bf16), q,k (affine, bf16)
// ---------------------------------------------------------------------------
__global__ __launch_bounds__(256) void k_gemm1(
    const u16* __restrict__ xb, const u16* __restrict__ WibT,
    const float* __restrict__ bi, const float* __restrict__ gq, const float* __restrict__ bq,
    const float* __restrict__ gk, const float* __restrict__ bk,
    u16* __restrict__ pu, u16* __restrict__ pv, u16* __restrict__ pq, u16* __restrict__ pk)
{
    __shared__ __align__(16) u16 lA[128 * 64];
    __shared__ __align__(16) u16 lB[128 * 64];
    f32x4 acc[4][4] = {};
    int m0 = blockIdx.x * 128, n0 = blockIdx.y * 128;
    gemm_mainloop(xb, 768, WibT, 768, 768, m0, n0, lA, lB, acc);

    EPILOGUE_COORDS();
    #pragma unroll
    for (int i = 0; i < 4; ++i)
        #pragma unroll
        for (int j = 0; j < 4; ++j)
            #pragma unroll
            for (int rr = 0; rr < 4; ++rr) {
                int m = m0 + wm + i * 16 + lq * 4 + rr;
                int n = n0 + wn + j * 16 + lr;
                float val = acc[i][j][rr] + bi[n];
                float s = val / (1.f + __expf(-val));   // silu
                if (n < 1536) {
                    pu[(size_t)m * 1536 + n] = f2bf(s);
                } else if (n < 3072) {
                    pv[(size_t)m * 1536 + (n - 1536)] = f2bf(s);
                } else {
                    int c = n - 3072;
                    pq[(size_t)m * 128 + c] = f2bf(s * gq[c] + bq[c]);
                    pk[(size_t)m * 128 + c] = f2bf(s * gk[c] + bk[c]);
                }
            }
}

// ---------------------------------------------------------------------------
// Scores: P = relu(q@k^T / sqrt(128))^2 / 4096   (per batch), bf16 out
// ---------------------------------------------------------------------------
__global__ __launch_bounds__(256) void k_scores(
    const u16* __restrict__ q, const u16* __restrict__ k, u16* __restrict__ P, int b0)
{
    __shared__ __align__(16) u16 lA[128 * 64];
    __shared__ __align__(16) u16 lB[128 * 64];
    f32x4 acc[4][4] = {};
    int bb = blockIdx.z;
    int b  = b0 + bb;
    const u16* A = q + (size_t)b * 4096 * 128;
    const u16* B = k + (size_t)b * 4096 * 128;
    int m0 = blockIdx.x * 128, n0 = blockIdx.y * 128;
    gemm_mainloop(A, 128, B, 128, 128, m0, n0, lA, lB, acc);

    u16* Pb = P + (size_t)bb * 4096 * 4096;
    const float sc = 1.f / (128.f * 4096.f);   // (x/sqrt(128))^2 / 4096
    EPILOGUE_COORDS();
    #pragma unroll
    for (int i = 0; i < 4; ++i)
        #pragma unroll
        for (int j = 0; j < 4; ++j)
            #pragma unroll
            for (int rr = 0; rr < 4; ++rr) {
                int m = m0 + wm + i * 16 + lq * 4 + rr;
                int n = n0 + wn + j * 16 + lr;
                float a = fmaxf(acc[i][j][rr], 0.f);
                Pb[(size_t)m * 4096 + n] = f2bf(a * a * sc);
            }
}

// ---------------------------------------------------------------------------
// PV: z = P @ v  (B-operand = vT, N x K);  epilogue uz = u * z in-place over u
// ---------------------------------------------------------------------------
__global__ __launch_bounds__(256) void k_zu(
    const u16* __restrict__ P, const u16* __restrict__ vT, u16* __restrict__ pu, int b0)
{
    __shared__ __align__(16) u16 lA[128 * 64];
    __shared__ __align__(16) u16 lB[128 * 64];
    f32x4 acc[4][4] = {};
    int bb = blockIdx.z;
    int b  = b0 + bb;
    const u16* A = P  + (size_t)bb * 4096 * 4096;   // 4096 x 4096
    const u16* B = vT + (size_t)b * 1536 * 4096;    // 1536 x 4096 (N x K)
    int m0 = blockIdx.x * 128, n0 = blockIdx.y * 128;
    gemm_mainloop(A, 4096, B, 4096, 4096, m0, n0, lA, lB, acc);

    EPILOGUE_COORDS();
    #pragma unroll
    for (int i = 0; i < 4; ++i)
        #pragma unroll
        for (int j = 0; j < 4; ++j)
            #pragma unroll
            for (int rr = 0; rr < 4; ++rr) {
                int m = m0 + wm + i * 16 + lq * 4 + rr;
                int n = n0 + wn + j * 16 + lr;
                size_t idx = (size_t)(b * 4096 + m) * 1536 + n;
                pu[idx] = f2bf(bf2f(pu[idx]) * acc[i][j][rr]);
            }
}

// ---------------------------------------------------------------------------
// GEMM3: o = (u*z) @ Wo + bo  -> f32 out
// ---------------------------------------------------------------------------
__global__ __launch_bounds__(256) void k_out(
    const u16* __restrict__ uz, const u16* __restrict__ WobT,
    const float* __restrict__ bo, float* __restrict__ out)
{
    __shared__ __align__(16) u16 lA[128 * 64];
    __shared__ __align__(16) u16 lB[128 * 64];
    f32x4 acc[4][4] = {};
    int m0 = blockIdx.x * 128, n0 = blockIdx.y * 128;
    gemm_mainloop(uz, 1536, WobT, 1536, 1536, m0, n0, lA, lB, acc);

    EPILOGUE_COORDS();
    #pragma unroll
    for (int i = 0; i < 4; ++i)
        #pragma unroll
        for (int j = 0; j < 4; ++j)
            #pragma unroll
            for (int rr = 0; rr < 4; ++rr) {
                int m = m0 + wm + i * 16 + lq * 4 + rr;
                int n = n0 + wn + j * 16 + lr;
                out[(size_t)m * 768 + n] = acc[i][j][rr] + bo[n];
            }
}

// ---------------------------------------------------------------------------
extern "C" void kernel_launch(void* const* d_in, const int* in_sizes, int n_in,
                              void* d_out, int out_size, void* d_ws, size_t ws_size,
                              hipStream_t stream)
{
    const float* x  = (const float*)d_in[0];
    const float* Wi = (const float*)d_in[1];
    const float* bi = (const float*)d_in[2];
    const float* gq = (const float*)d_in[3];
    const float* bq = (const float*)d_in[4];
    const float* gk = (const float*)d_in[5];
    const float* bk = (const float*)d_in[6];
    const float* Wo = (const float*)d_in[7];
    const float* bo = (const float*)d_in[8];
    float* out = (float*)d_out;

    char* ws = (char*)d_ws;
    size_t off = 0;
    auto alloc = [&](size_t bytes) -> void* {
        void* p = ws + off;
        off += (bytes + 255) & ~(size_t)255;
        return p;
    };
    u16* xb   = (u16*)alloc((size_t)16384 * 768 * 2);
    u16* WibT = (u16*)alloc((size_t)3200 * 768 * 2);
    u16* WobT = (u16*)alloc((size_t)768 * 1536 * 2);
    u16* u    = (u16*)alloc((size_t)16384 * 1536 * 2);   // becomes uz in-place
    u16* v    = (u16*)alloc((size_t)16384 * 1536 * 2);
    u16* vT   = (u16*)alloc((size_t)4 * 1536 * 4096 * 2);
    u16* q    = (u16*)alloc((size_t)16384 * 128 * 2);
    u16* k    = (u16*)alloc((size_t)16384 * 128 * 2);
    u16* P    = (u16*)alloc((size_t)2 * 4096 * 4096 * 2); // 2-batch chunk

    k_cast_x<<<dim3(12288), dim3(256), 0, stream>>>(x, xb);
    k_transpose_w<<<dim3(3200 / 32, 768 / 32), dim3(32, 8), 0, stream>>>(Wi, WibT, 768, 3200);
    k_transpose_w<<<dim3(768 / 32, 1536 / 32), dim3(32, 8), 0, stream>>>(Wo, WobT, 1536, 768);

    k_gemm1<<<dim3(16384 / 128, 3200 / 128), dim3(256), 0, stream>>>(
        xb, WibT, bi, gq, bq, gk, bk, u, v, q, k);

    k_transpose_v<<<dim3(64, 24, 4), dim3(256), 0, stream>>>(v, vT);

    for (int b0 = 0; b0 < 4; b0 += 2) {
        k_scores<<<dim3(32, 32, 2), dim3(256), 0, stream>>>(q, k, P, b0);
        k_zu<<<dim3(32, 1536 / 128, 2), dim3(256), 0, stream>>>(P, vT, u, b0);
    }

    k_out<<<dim3(16384 / 128, 768 / 128), dim3(256), 0, stream>>>(u, WobT, bo, out);
}

// Round 2
// 526.245 us; speedup vs baseline: 1.3099x; 1.3099x over previous
//
#include <hip/hip_runtime.h>
#include <hip/hip_bf16.h>

typedef unsigned short u16;
typedef __bf16 bf16x8 __attribute__((ext_vector_type(8)));
typedef float f32x4 __attribute__((ext_vector_type(4)));

#define DEVI __device__ __forceinline__

DEVI u16 f2bf(float f) {
    unsigned u = __builtin_bit_cast(unsigned, f);
    u += 0x7fff + ((u >> 16) & 1);   // RNE; inputs are finite
    return (u16)(u >> 16);
}
DEVI float bf2f(u16 h) {
    unsigned u = ((unsigned)h) << 16;
    return __builtin_bit_cast(float, u);
}

typedef __attribute__((address_space(1))) const unsigned GU32;
typedef __attribute__((address_space(3))) unsigned LU32;

DEVI void gload_lds16(const void* g, void* l) {
    __builtin_amdgcn_global_load_lds((GU32*)g, (LU32*)l, 16, 0, 0);
}

// ===========================================================================
// 256x256 8-phase GEMM mainloop (HK-style schedule in plain HIP).
//   C[256x256] += A[Mx K] * B^T   (B stored N x K row-major)
//   512 threads = 8 waves (2 M x 4 N); per-wave output 128x64 as 8x4 frags
//   of mfma_f32_16x16x32_bf16. BK=64 split into 2 K-halves of 32.
//   LDS = [buf2][kh2][mat2][256 rows][32 cols] bf16 = 128 KiB.
//   Staging: 1 half-tile (16KB, 2 gload_lds16/thread) per phase, lead = 1
//   K-tile; counted s_waitcnt vmcnt(4) at each kh boundary (never 0 except
//   the final tile); raw s_barrier; T2 XOR swizzle (inverse-swizzled global
//   source + swizzled ds_read, linear LDS dest); T5 setprio around MFMA.
// ===========================================================================

// Stage one 16KB half-tile: rows [0,256) x 32 cols at column kcol.
// Physical LDS is linear; global source column is inverse-swizzled so that
// the swizzled ds_read below recovers logical data (involution).
DEVI void stage_half(const u16* __restrict__ src, int ld, int rowbase, int kcol,
                     u16* region, int wave, int lane)
{
    #pragma unroll
    for (int g = 0; g < 2; ++g) {
        int seg  = wave * 2 + g;                      // 16 segments of 1024B
        int r    = seg * 16 + (lane >> 2);            // row within 256
        int slog = (lane & 3) ^ ((lane >> 3) & 3);    // logical 16B slot = sphys ^ ((r>>1)&3)
        gload_lds16(src + (size_t)(rowbase + r) * ld + kcol + slog * 8,
                    region + seg * 512);
    }
}

template<int MH>
DEVI void phase16(const u16* RA, const u16* RB,
                  int wr, int wc, int lr, int lq, f32x4 (&acc)[8][4])
{
    bf16x8 af[4], bv[4];
    #pragma unroll
    for (int q = 0; q < 4; ++q) {
        int ra = wr * 128 + (MH * 4 + q) * 16 + lr;
        af[q] = *(const bf16x8*)((const char*)RA + ra * 64 + ((lq * 16) ^ (((ra >> 1) & 3) << 4)));
    }
    #pragma unroll
    for (int nj = 0; nj < 4; ++nj) {
        int rb = wc * 64 + nj * 16 + lr;
        bv[nj] = *(const bf16x8*)((const char*)RB + rb * 64 + ((lq * 16) ^ (((rb >> 1) & 3) << 4)));
    }
    __builtin_amdgcn_s_setprio(1);
    #pragma unroll
    for (int q = 0; q < 4; ++q)
        #pragma unroll
        for (int nj = 0; nj < 4; ++nj)
            acc[MH * 4 + q][nj] =
                __builtin_amdgcn_mfma_f32_16x16x32_bf16(af[q], bv[nj], acc[MH * 4 + q][nj], 0, 0, 0);
    __builtin_amdgcn_s_setprio(0);
}

DEVI void gemm8(const u16* __restrict__ A, int lda,
                const u16* __restrict__ B, int ldb,
                int NT, int m0, int n0, u16* lds, f32x4 (&acc)[8][4])
{
    const int tid = threadIdx.x;
    const int wave = tid >> 6, lane = tid & 63;
    const int lr = lane & 15, lq = lane >> 4;
    const int wr = wave >> 2, wc = wave & 3;

    auto reg = [&](int p, int kh, int m) -> u16* {
        return lds + (((p * 2 + kh) * 2 + m) << 13);   // 8192 elements per region
    };

    // Prologue: stage tile 0 (both K-halves); need kh0 before phase 1.
    stage_half(A, lda, m0, 0,  reg(0, 0, 0), wave, lane);
    stage_half(B, ldb, n0, 0,  reg(0, 0, 1), wave, lane);
    stage_half(A, lda, m0, 32, reg(0, 1, 0), wave, lane);
    stage_half(B, ldb, n0, 32, reg(0, 1, 1), wave, lane);
    asm volatile("s_waitcnt vmcnt(4)" ::: "memory");
    __builtin_amdgcn_s_barrier();

    for (int t = 0; t < NT; ++t) {
        const int p = t & 1;
        const bool last = (t == NT - 1);
        const int k1 = (t + 1) * 64;
        const u16* rA0 = reg(p, 0, 0); const u16* rB0 = reg(p, 0, 1);
        const u16* rA1 = reg(p, 1, 0); const u16* rB1 = reg(p, 1, 1);

        // --- kh0 phases (consume buf p kh0; stage next tile's kh0) ---
        if (!last) stage_half(A, lda, m0, k1, reg(p ^ 1, 0, 0), wave, lane);
        phase16<0>(rA0, rB0, wr, wc, lr, lq, acc);
        if (!last) stage_half(B, ldb, n0, k1, reg(p ^ 1, 0, 1), wave, lane);
        phase16<1>(rA0, rB0, wr, wc, lr, lq, acc);
        // own tile's kh1 halves guaranteed done (4 newest outstanding = next kh0)
        if (last) { asm volatile("s_waitcnt vmcnt(0)" ::: "memory"); }
        else      { asm volatile("s_waitcnt vmcnt(4)" ::: "memory"); }
        __builtin_amdgcn_s_barrier();

        // --- kh1 phases (consume buf p kh1; stage next tile's kh1) ---
        if (!last) stage_half(A, lda, m0, k1 + 32, reg(p ^ 1, 1, 0), wave, lane);
        phase16<0>(rA1, rB1, wr, wc, lr, lq, acc);
        if (!last) stage_half(B, ldb, n0, k1 + 32, reg(p ^ 1, 1, 1), wave, lane);
        phase16<1>(rA1, rB1, wr, wc, lr, lq, acc);
        if (!last) {
            // next tile's kh0 halves guaranteed done (4 newest = next kh1)
            asm volatile("s_waitcnt vmcnt(4)" ::: "memory");
            __builtin_amdgcn_s_barrier();
        }
    }
}

// Output coords: row = m0 + wr*128 + mi*16 + lq*4 + rr, col = n0 + wc*64 + nj*16 + lr
#define EPI_COORDS()                                        \
    const int tid = threadIdx.x;                            \
    const int wave = tid >> 6, lane = tid & 63;             \
    const int lr = lane & 15, lq = lane >> 4;               \
    const int wr = wave >> 2, wc = wave & 3;                \
    (void)tid;

// ---------------------------------------------------------------------------
// Prep kernels
// ---------------------------------------------------------------------------
__global__ __launch_bounds__(256) void k_cast_x(const float* __restrict__ x, u16* __restrict__ xb)
{
    size_t i = (size_t)blockIdx.x * 256 + threadIdx.x;   // one float4 per thread
    float4 f = ((const float4*)x)[i];
    ushort4 o;
    o.x = f2bf(f.x); o.y = f2bf(f.y); o.z = f2bf(f.z); o.w = f2bf(f.w);
    ((ushort4*)xb)[i] = o;
}

// in: R x C f32 row-major -> out: Cout x R bf16 row-major, zero-fill c >= C.
// Grid: (Cout/32, R/32). Cout implied by grid.
__global__ void k_transpose_w(const float* __restrict__ in, u16* __restrict__ out, int R, int C)
{
    __shared__ u16 t[32][33];
    int c0 = blockIdx.x * 32, r0 = blockIdx.y * 32;
    int tx = threadIdx.x, ty = threadIdx.y;
    #pragma unroll
    for (int p = 0; p < 4; ++p) {
        int rr = ty + p * 8;
        int c = c0 + tx;
        t[rr][tx] = (c < C) ? f2bf(in[(size_t)(r0 + rr) * C + c]) : (u16)0;
    }
    __syncthreads();
    #pragma unroll
    for (int p = 0; p < 4; ++p) {
        int cc = ty + p * 8;
        out[(size_t)(c0 + cc) * R + r0 + tx] = t[tx][cc];
    }
}

// v [B*4096 x 1536] bf16 -> vT [B][1536][4096] bf16
__global__ __launch_bounds__(256) void k_transpose_v(const u16* __restrict__ v, u16* __restrict__ vT)
{
    __shared__ u16 t[64][72];
    int b = blockIdx.z;
    int n0 = blockIdx.x * 64, d0 = blockIdx.y * 64;
    int tid = threadIdx.x;
    #pragma unroll
    for (int p = 0; p < 2; ++p) {
        int row = (tid >> 3) + p * 32;        // n
        int cg  = (tid & 7) * 8;              // d
        uint4 w = *(const uint4*)(v + (size_t)(b * 4096 + n0 + row) * 1536 + d0 + cg);
        *(uint4*)&t[row][cg] = w;
    }
    __syncthreads();
    #pragma unroll
    for (int p = 0; p < 2; ++p) {
        int dr = (tid >> 3) + p * 32;         // d
        int nc = (tid & 7) * 8;               // n
        u16 tmp[8];
        #pragma unroll
        for (int e = 0; e < 8; ++e) tmp[e] = t[nc + e][dr];
        *(uint4*)(vT + (size_t)b * 1536 * 4096 + (size_t)(d0 + dr) * 4096 + n0 + nc) = *(const uint4*)tmp;
    }
}

// ---------------------------------------------------------------------------
// GEMM1: h = silu(x@Wi + bi); split -> u, v (bf16), q,k (affine, bf16)
// N padded 3200 -> 3328 (13 tiles); by selects block-uniform region.
// ---------------------------------------------------------------------------
__global__ __launch_bounds__(512, 2) void k_gemm1(
    const u16* __restrict__ xb, const u16* __restrict__ WibT,
    const float* __restrict__ bi, const float* __restrict__ gq, const float* __restrict__ bq,
    const float* __restrict__ gk, const float* __restrict__ bk,
    u16* __restrict__ pu, u16* __restrict__ pv, u16* __restrict__ pq, u16* __restrict__ pk)
{
    __shared__ __align__(16) u16 lds[8 * 8192];
    f32x4 acc[8][4] = {};
    int m0 = blockIdx.x * 256, n0 = blockIdx.y * 256;
    gemm8(xb, 768, WibT, 768, 12, m0, n0, lds, acc);

    EPI_COORDS();
    int by = blockIdx.y;
    if (by < 6) {
        #pragma unroll
        for (int mi = 0; mi < 8; ++mi)
            #pragma unroll
            for (int nj = 0; nj < 4; ++nj)
                #pragma unroll
                for (int rr = 0; rr < 4; ++rr) {
                    int m = m0 + wr * 128 + mi * 16 + lq * 4 + rr;
                    int n = n0 + wc * 64 + nj * 16 + lr;
                    float val = acc[mi][nj][rr] + bi[n];
                    float s = val / (1.f + __expf(-val));
                    pu[(size_t)m * 1536 + n] = f2bf(s);
                }
    } else if (by < 12) {
        #pragma unroll
        for (int mi = 0; mi < 8; ++mi)
            #pragma unroll
            for (int nj = 0; nj < 4; ++nj)
                #pragma unroll
                for (int rr = 0; rr < 4; ++rr) {
                    int m = m0 + wr * 128 + mi * 16 + lq * 4 + rr;
                    int n = n0 + wc * 64 + nj * 16 + lr;
                    float val = acc[mi][nj][rr] + bi[n];
                    float s = val / (1.f + __expf(-val));
                    pv[(size_t)m * 1536 + (n - 1536)] = f2bf(s);
                }
    } else if (wc < 2) {   // qk region: cols 3072..3199 real, rest pad
        #pragma unroll
        for (int mi = 0; mi < 8; ++mi)
            #pragma unroll
            for (int nj = 0; nj < 4; ++nj)
                #pragma unroll
                for (int rr = 0; rr < 4; ++rr) {
                    int m = m0 + wr * 128 + mi * 16 + lq * 4 + rr;
                    int n = n0 + wc * 64 + nj * 16 + lr;
                    int c = n - 3072;
                    float val = acc[mi][nj][rr] + bi[n];
                    float s = val / (1.f + __expf(-val));
                    pq[(size_t)m * 128 + c] = f2bf(s * gq[c] + bq[c]);
                    pk[(size_t)m * 128 + c] = f2bf(s * gk[c] + bk[c]);
                }
    }
}

// ---------------------------------------------------------------------------
// Scores: P = relu(q@k^T / sqrt(128))^2 / 4096  (per batch), bf16 out
// ---------------------------------------------------------------------------
__global__ __launch_bounds__(512, 2) void k_scores(
    const u16* __restrict__ q, const u16* __restrict__ k, u16* __restrict__ P, int b0)
{
    __shared__ __align__(16) u16 lds[8 * 8192];
    f32x4 acc[8][4] = {};
    int bb = blockIdx.z;
    int b  = b0 + bb;
    const u16* A = q + (size_t)b * 4096 * 128;
    const u16* B = k + (size_t)b * 4096 * 128;
    int m0 = blockIdx.x * 256, n0 = blockIdx.y * 256;
    gemm8(A, 128, B, 128, 2, m0, n0, lds, acc);

    u16* Pb = P + (size_t)bb * 4096 * 4096;
    const float sc = 1.f / (128.f * 4096.f);
    EPI_COORDS();
    #pragma unroll
    for (int mi = 0; mi < 8; ++mi)
        #pragma unroll
        for (int nj = 0; nj < 4; ++nj)
            #pragma unroll
            for (int rr = 0; rr < 4; ++rr) {
                int m = m0 + wr * 128 + mi * 16 + lq * 4 + rr;
                int n = n0 + wc * 64 + nj * 16 + lr;
                float a = fmaxf(acc[mi][nj][rr], 0.f);
                Pb[(size_t)m * 4096 + n] = f2bf(a * a * sc);
            }
}

// ---------------------------------------------------------------------------
// PV: z = P @ v  (B = vT, N x K);  epilogue uz = u * z in-place over u
// ---------------------------------------------------------------------------
__global__ __launch_bounds__(512, 2) void k_zu(
    const u16* __restrict__ P, const u16* __restrict__ vT, u16* __restrict__ pu, int b0)
{
    __shared__ __align__(16) u16 lds[8 * 8192];
    f32x4 acc[8][4] = {};
    int bb = blockIdx.z;
    int b  = b0 + bb;
    const u16* A = P  + (size_t)bb * 4096 * 4096;   // 4096 x 4096
    const u16* B = vT + (size_t)b * 1536 * 4096;    // 1536 x 4096 (N x K)
    int m0 = blockIdx.x * 256, n0 = blockIdx.y * 256;
    gemm8(A, 4096, B, 4096, 64, m0, n0, lds, acc);

    EPI_COORDS();
    #pragma unroll
    for (int mi = 0; mi < 8; ++mi)
        #pragma unroll
        for (int nj = 0; nj < 4; ++nj)
            #pragma unroll
            for (int rr = 0; rr < 4; ++rr) {
                int m = m0 + wr * 128 + mi * 16 + lq * 4 + rr;
                int n = n0 + wc * 64 + nj * 16 + lr;
                size_t idx = (size_t)(b * 4096 + m) * 1536 + n;
                pu[idx] = f2bf(bf2f(pu[idx]) * acc[mi][nj][rr]);
            }
}

// ---------------------------------------------------------------------------
// GEMM3: o = (u*z) @ Wo + bo  -> f32 out
// ---------------------------------------------------------------------------
__global__ __launch_bounds__(512, 2) void k_out(
    const u16* __restrict__ uz, const u16* __restrict__ WobT,
    const float* __restrict__ bo, float* __restrict__ out)
{
    __shared__ __align__(16) u16 lds[8 * 8192];
    f32x4 acc[8][4] = {};
    int m0 = blockIdx.x * 256, n0 = blockIdx.y * 256;
    gemm8(uz, 1536, WobT, 1536, 24, m0, n0, lds, acc);

    EPI_COORDS();
    #pragma unroll
    for (int mi = 0; mi < 8; ++mi)
        #pragma unroll
        for (int nj = 0; nj < 4; ++nj)
            #pragma unroll
            for (int rr = 0; rr < 4; ++rr) {
                int m = m0 + wr * 128 + mi * 16 + lq * 4 + rr;
                int n = n0 + wc * 64 + nj * 16 + lr;
                out[(size_t)m * 768 + n] = acc[mi][nj][rr] + bo[n];
            }
}

// ---------------------------------------------------------------------------
extern "C" void kernel_launch(void* const* d_in, const int* in_sizes, int n_in,
                              void* d_out, int out_size, void* d_ws, size_t ws_size,
                              hipStream_t stream)
{
    const float* x  = (const float*)d_in[0];
    const float* Wi = (const float*)d_in[1];
    const float* bi = (const float*)d_in[2];
    const float* gq = (const float*)d_in[3];
    const float* bq = (const float*)d_in[4];
    const float* gk = (const float*)d_in[5];
    const float* bk = (const float*)d_in[6];
    const float* Wo = (const float*)d_in[7];
    const float* bo = (const float*)d_in[8];
    float* out = (float*)d_out;

    char* ws = (char*)d_ws;
    size_t off = 0;
    auto alloc = [&](size_t bytes) -> void* {
        void* p = ws + off;
        off += (bytes + 255) & ~(size_t)255;
        return p;
    };
    u16* xb   = (u16*)alloc((size_t)16384 * 768 * 2);
    u16* WibT = (u16*)alloc((size_t)3328 * 768 * 2);     // padded N: 3200 -> 3328
    u16* WobT = (u16*)alloc((size_t)768 * 1536 * 2);
    u16* u    = (u16*)alloc((size_t)16384 * 1536 * 2);   // becomes uz in-place
    u16* v    = (u16*)alloc((size_t)16384 * 1536 * 2);
    u16* vT   = (u16*)alloc((size_t)4 * 1536 * 4096 * 2);
    u16* q    = (u16*)alloc((size_t)16384 * 128 * 2);
    u16* k    = (u16*)alloc((size_t)16384 * 128 * 2);
    u16* P    = (u16*)alloc((size_t)2 * 4096 * 4096 * 2); // 2-batch chunk

    k_cast_x<<<dim3(12288), dim3(256), 0, stream>>>(x, xb);
    k_transpose_w<<<dim3(3328 / 32, 768 / 32), dim3(32, 8), 0, stream>>>(Wi, WibT, 768, 3200);
    k_transpose_w<<<dim3(768 / 32, 1536 / 32), dim3(32, 8), 0, stream>>>(Wo, WobT, 1536, 768);

    k_gemm1<<<dim3(64, 13), dim3(512), 0, stream>>>(
        xb, WibT, bi, gq, bq, gk, bk, u, v, q, k);

    k_transpose_v<<<dim3(64, 24, 4), dim3(256), 0, stream>>>(v, vT);

    for (int b0 = 0; b0 < 4; b0 += 2) {
        k_scores<<<dim3(16, 16, 2), dim3(512), 0, stream>>>(q, k, P, b0);
        k_zu<<<dim3(16, 6, 2), dim3(512), 0, stream>>>(P, vT, u, b0);
    }

    k_out<<<dim3(64, 3), dim3(512), 0, stream>>>(u, WobT, bo, out);
}

// Round 3
// 451.143 us; speedup vs baseline: 1.5279x; 1.1665x over previous
//
#include <hip/hip_runtime.h>
#include <hip/hip_bf16.h>

typedef unsigned short u16;
typedef __bf16 bf16x8 __attribute__((ext_vector_type(8)));
typedef float f32x4 __attribute__((ext_vector_type(4)));

#define DEVI __device__ __forceinline__

DEVI u16 f2bf(float f) {
    unsigned u = __builtin_bit_cast(unsigned, f);
    u += 0x7fff + ((u >> 16) & 1);   // RNE; inputs are finite
    return (u16)(u >> 16);
}
DEVI float bf2f(u16 h) {
    unsigned u = ((unsigned)h) << 16;
    return __builtin_bit_cast(float, u);
}

typedef __attribute__((address_space(1))) const unsigned GU32;
typedef __attribute__((address_space(3))) unsigned LU32;

DEVI void gload_lds16(const void* g, void* l) {
    __builtin_amdgcn_global_load_lds((GU32*)g, (LU32*)l, 16, 0, 0);
}

// Bijective XCD-chunk swizzle (m204): consecutive logical ids land on the
// same XCD. All our grid sizes are multiples of 8.
DEVI int xcd_swz(int orig, int n) {
    int q = n >> 3, r = n & 7, x = orig & 7, o = orig >> 3;
    return (x < r ? x * (q + 1) : r * (q + 1) + (x - r) * q) + o;
}

// ===========================================================================
// 256x256 8-phase GEMM mainloop. C[256x256] += A[MxK] * B^T (B: N x K row-maj)
// 512 thr = 8 waves (2M x 4N); per-wave 128x64 out as 8x4 frags of
// mfma_f32_16x16x32_bf16. BK=64 in 2 K-halves; LDS [buf2][kh2][mat2][256][32]
// = 128 KiB; counted vmcnt(4); T2 XOR swizzle; T5 setprio.
// Addressing strength-reduced: persistent global pointers + precomputed
// LDS byte offsets (keeps mainloop VALU minimal regardless of epilogue).
// ===========================================================================
template<int MH>
DEVI void phase16(const u16* RA, const u16* RB,
                  const int (&offA)[2][4], const int (&offB)[4], f32x4 (&acc)[8][4])
{
    bf16x8 af[4], bv[4];
    #pragma unroll
    for (int q = 0; q < 4; ++q)
        af[q] = *(const bf16x8*)((const char*)RA + offA[MH][q]);
    #pragma unroll
    for (int nj = 0; nj < 4; ++nj)
        bv[nj] = *(const bf16x8*)((const char*)RB + offB[nj]);
    __builtin_amdgcn_s_setprio(1);
    #pragma unroll
    for (int q = 0; q < 4; ++q)
        #pragma unroll
        for (int nj = 0; nj < 4; ++nj)
            acc[MH * 4 + q][nj] =
                __builtin_amdgcn_mfma_f32_16x16x32_bf16(af[q], bv[nj], acc[MH * 4 + q][nj], 0, 0, 0);
    __builtin_amdgcn_s_setprio(0);
}

DEVI void gemm8(const u16* __restrict__ A, int lda,
                const u16* __restrict__ B, int ldb,
                int NT, int m0, int n0, u16* lds, f32x4 (&acc)[8][4])
{
    const int tid = threadIdx.x;
    const int wave = tid >> 6, lane = tid & 63;
    const int lr = lane & 15, lq = lane >> 4;
    const int wr = wave >> 2, wc = wave & 3;

    // Precomputed swizzled ds_read byte offsets (region-relative).
    int offA[2][4], offB[4];
    #pragma unroll
    for (int mh = 0; mh < 2; ++mh)
        #pragma unroll
        for (int qq = 0; qq < 4; ++qq) {
            int ra = wr * 128 + (mh * 4 + qq) * 16 + lr;
            offA[mh][qq] = ra * 64 + ((lq * 16) ^ (((ra >> 1) & 3) << 4));
        }
    #pragma unroll
    for (int nj = 0; nj < 4; ++nj) {
        int rb = wc * 64 + nj * 16 + lr;
        offB[nj] = rb * 64 + ((lq * 16) ^ (((rb >> 1) & 3) << 4));
    }

    // Persistent staging pointers (inverse-swizzled source column).
    const int rstage = wave * 32 + (lane >> 2);            // wave covers rows [32w, 32w+32)
    const int slog   = (lane & 3) ^ ((lane >> 3) & 3);
    const u16* pA = A + (size_t)(m0 + rstage) * lda + slog * 8;
    const u16* pB = B + (size_t)(n0 + rstage) * ldb + slog * 8;
    const size_t sA16 = (size_t)16 * lda, sB16 = (size_t)16 * ldb;
    const int wdst = wave * 1024;                          // seg pair dest base

    auto reg = [&](int p, int kh, int m) -> u16* {
        return lds + (((p * 2 + kh) * 2 + m) << 13);       // 8192 elems/region
    };

#define STAGE_A(p, kh) do { u16* d_ = reg(p, kh, 0) + wdst; \
        gload_lds16(pA, d_); gload_lds16(pA + sA16, d_ + 512); pA += 32; } while (0)
#define STAGE_B(p, kh) do { u16* d_ = reg(p, kh, 1) + wdst; \
        gload_lds16(pB, d_); gload_lds16(pB + sB16, d_ + 512); pB += 32; } while (0)

    // Prologue: stage tile 0 (both K-halves).
    STAGE_A(0, 0); STAGE_B(0, 0);
    STAGE_A(0, 1); STAGE_B(0, 1);
    asm volatile("s_waitcnt vmcnt(4)" ::: "memory");
    __builtin_amdgcn_s_barrier();

    for (int t = 0; t < NT; ++t) {
        const int p = t & 1;
        const bool last = (t == NT - 1);
        const u16* rA0 = reg(p, 0, 0); const u16* rB0 = reg(p, 0, 1);
        const u16* rA1 = reg(p, 1, 0); const u16* rB1 = reg(p, 1, 1);

        // --- kh0 phases (consume buf p kh0; stage next tile's kh0) ---
        if (!last) STAGE_A(p ^ 1, 0);
        phase16<0>(rA0, rB0, offA, offB, acc);
        if (!last) STAGE_B(p ^ 1, 0);
        phase16<1>(rA0, rB0, offA, offB, acc);
        if (last) { asm volatile("s_waitcnt vmcnt(0)" ::: "memory"); }
        else      { asm volatile("s_waitcnt vmcnt(4)" ::: "memory"); }
        __builtin_amdgcn_s_barrier();

        // --- kh1 phases (consume buf p kh1; stage next tile's kh1) ---
        if (!last) STAGE_A(p ^ 1, 1);
        phase16<0>(rA1, rB1, offA, offB, acc);
        if (!last) STAGE_B(p ^ 1, 1);
        phase16<1>(rA1, rB1, offA, offB, acc);
        if (!last) {
            asm volatile("s_waitcnt vmcnt(4)" ::: "memory");
            __builtin_amdgcn_s_barrier();
        }
    }
#undef STAGE_A
#undef STAGE_B
}

// Output coords: row = m0 + wr*128 + mi*16 + lq*4 + rr, col = n0 + wc*64 + nj*16 + lr
#define EPI_COORDS()                                        \
    const int tid = threadIdx.x;                            \
    const int wave = tid >> 6, lane = tid & 63;             \
    const int lr = lane & 15, lq = lane >> 4;               \
    const int wr = wave >> 2, wc = wave & 3;                \
    (void)tid;

// ---------------------------------------------------------------------------
// Prep kernels
// ---------------------------------------------------------------------------
__global__ __launch_bounds__(256) void k_cast_x(const float* __restrict__ x, u16* __restrict__ xb)
{
    size_t i = (size_t)blockIdx.x * 256 + threadIdx.x;
    float4 f = ((const float4*)x)[i];
    ushort4 o;
    o.x = f2bf(f.x); o.y = f2bf(f.y); o.z = f2bf(f.z); o.w = f2bf(f.w);
    ((ushort4*)xb)[i] = o;
}

// in: R x C f32 row-major -> out: Cout x R bf16 row-major, zero-fill c >= C.
__global__ void k_transpose_w(const float* __restrict__ in, u16* __restrict__ out, int R, int C)
{
    __shared__ u16 t[32][33];
    int c0 = blockIdx.x * 32, r0 = blockIdx.y * 32;
    int tx = threadIdx.x, ty = threadIdx.y;
    #pragma unroll
    for (int p = 0; p < 4; ++p) {
        int rr = ty + p * 8;
        int c = c0 + tx;
        t[rr][tx] = (c < C) ? f2bf(in[(size_t)(r0 + rr) * C + c]) : (u16)0;
    }
    __syncthreads();
    #pragma unroll
    for (int p = 0; p < 4; ++p) {
        int cc = ty + p * 8;
        out[(size_t)(c0 + cc) * R + r0 + tx] = t[tx][cc];
    }
}

// ---------------------------------------------------------------------------
// GEMM1: h = x@Wi (raw acc, bf16) -> h[16384][3328]. Minimal epilogue.
// ---------------------------------------------------------------------------
__global__ __launch_bounds__(512, 2) void k_gemm1(
    const u16* __restrict__ xb, const u16* __restrict__ WibT, u16* __restrict__ h)
{
    __shared__ __align__(16) u16 lds[8 * 8192];
    f32x4 acc[8][4] = {};
    int L = xcd_swz(blockIdx.x, 832);
    int m0 = (L / 13) * 256, n0 = (L % 13) * 256;
    gemm8(xb, 768, WibT, 768, 12, m0, n0, lds, acc);

    EPI_COORDS();
    #pragma unroll
    for (int mi = 0; mi < 8; ++mi)
        #pragma unroll
        for (int nj = 0; nj < 4; ++nj)
            #pragma unroll
            for (int rr = 0; rr < 4; ++rr) {
                int m = m0 + wr * 128 + mi * 16 + lq * 4 + rr;
                int n = n0 + wc * 64 + nj * 16 + lr;
                h[(size_t)m * 3328 + n] = f2bf(acc[mi][nj][rr]);
            }
}

// ---------------------------------------------------------------------------
// Split pass: silu(h+bi) -> u in-place (cols 0..1535), vT (transposed),
// q/k (affine). Memory-bound; replaces k_transpose_v.
// Grid (256, 50), 256 thr; 64x64 tile per block.
// ---------------------------------------------------------------------------
__global__ __launch_bounds__(256) void k_split(
    u16* __restrict__ h, const float* __restrict__ bi,
    const float* __restrict__ gq, const float* __restrict__ bq,
    const float* __restrict__ gk, const float* __restrict__ bk,
    u16* __restrict__ vT, u16* __restrict__ pq, u16* __restrict__ pk)
{
    const int m0 = blockIdx.x * 64, n0 = blockIdx.y * 64;
    const int tid = threadIdx.x;
    const int rrow = tid >> 2, c0 = (tid & 3) * 16;

    if (n0 < 1536) {                       // u region: in-place silu
        size_t base = (size_t)(m0 + rrow) * 3328 + n0 + c0;
        #pragma unroll
        for (int g = 0; g < 2; ++g) {
            bf16x8 hv = *(const bf16x8*)(h + base + g * 8);
            u16 ov[8];
            #pragma unroll
            for (int e = 0; e < 8; ++e) {
                float val = (float)hv[e] + bi[n0 + c0 + g * 8 + e];
                ov[e] = f2bf(val / (1.f + __expf(-val)));
            }
            *(uint4*)(h + base + g * 8) = *(const uint4*)ov;
        }
    } else if (n0 < 3072) {                // v region: silu + transpose -> vT
        __shared__ u16 t[64][72];
        size_t base = (size_t)(m0 + rrow) * 3328 + n0 + c0;
        #pragma unroll
        for (int g = 0; g < 2; ++g) {
            bf16x8 hv = *(const bf16x8*)(h + base + g * 8);
            #pragma unroll
            for (int e = 0; e < 8; ++e) {
                float val = (float)hv[e] + bi[n0 + c0 + g * 8 + e];
                t[rrow][c0 + g * 8 + e] = f2bf(val / (1.f + __expf(-val)));
            }
        }
        __syncthreads();
        const int b = m0 >> 12, mm = m0 & 4095, d0 = n0 - 1536;
        #pragma unroll
        for (int p = 0; p < 2; ++p) {
            int dr = (tid >> 3) + p * 32;
            int nc = (tid & 7) * 8;
            u16 tmp[8];
            #pragma unroll
            for (int e = 0; e < 8; ++e) tmp[e] = t[nc + e][dr];
            *(uint4*)(vT + (size_t)b * 1536 * 4096 + (size_t)(d0 + dr) * 4096 + mm + nc) = *(const uint4*)tmp;
        }
    } else {                               // qk region: silu + affine
        size_t base = (size_t)(m0 + rrow) * 3328 + n0 + c0;
        int cb = n0 + c0 - 3072;
        u16 qv[16], kv[16];
        #pragma unroll
        for (int g = 0; g < 2; ++g) {
            bf16x8 hv = *(const bf16x8*)(h + base + g * 8);
            #pragma unroll
            for (int e = 0; e < 8; ++e) {
                int c = cb + g * 8 + e;
                float val = (float)hv[e] + bi[3072 + c];
                float s = val / (1.f + __expf(-val));
                qv[g * 8 + e] = f2bf(s * gq[c] + bq[c]);
                kv[g * 8 + e] = f2bf(s * gk[c] + bk[c]);
            }
        }
        size_t ob = (size_t)(m0 + rrow) * 128 + cb;
        *(uint4*)(pq + ob)     = *(const uint4*)qv;
        *(uint4*)(pq + ob + 8) = *(const uint4*)(qv + 8);
        *(uint4*)(pk + ob)     = *(const uint4*)kv;
        *(uint4*)(pk + ob + 8) = *(const uint4*)(kv + 8);
    }
}

// ---------------------------------------------------------------------------
// Scores: P = relu(q@k^T / sqrt(128))^2 / 4096  (per batch), bf16 out
// ---------------------------------------------------------------------------
__global__ __launch_bounds__(512, 2) void k_scores(
    const u16* __restrict__ q, const u16* __restrict__ k, u16* __restrict__ P, int b0)
{
    __shared__ __align__(16) u16 lds[8 * 8192];
    f32x4 acc[8][4] = {};
    int bb = blockIdx.y;
    int b  = b0 + bb;
    const u16* A = q + (size_t)b * 4096 * 128;
    const u16* B = k + (size_t)b * 4096 * 128;
    int L = xcd_swz(blockIdx.x, 256);
    int m0 = (L >> 4) * 256, n0 = (L & 15) * 256;
    gemm8(A, 128, B, 128, 2, m0, n0, lds, acc);

    u16* Pb = P + (size_t)bb * 4096 * 4096;
    const float sc = 1.f / (128.f * 4096.f);
    EPI_COORDS();
    #pragma unroll
    for (int mi = 0; mi < 8; ++mi)
        #pragma unroll
        for (int nj = 0; nj < 4; ++nj)
            #pragma unroll
            for (int rr = 0; rr < 4; ++rr) {
                int m = m0 + wr * 128 + mi * 16 + lq * 4 + rr;
                int n = n0 + wc * 64 + nj * 16 + lr;
                float a = fmaxf(acc[mi][nj][rr], 0.f);
                Pb[(size_t)m * 4096 + n] = f2bf(a * a * sc);
            }
}

// ---------------------------------------------------------------------------
// PV: z = P @ v (B = vT); epilogue uz = u * z in place over h's u-region
// ---------------------------------------------------------------------------
__global__ __launch_bounds__(512, 2) void k_zu(
    const u16* __restrict__ P, const u16* __restrict__ vT, u16* __restrict__ h, int b0)
{
    __shared__ __align__(16) u16 lds[8 * 8192];
    f32x4 acc[8][4] = {};
    int bb = blockIdx.y;
    int b  = b0 + bb;
    const u16* A = P  + (size_t)bb * 4096 * 4096;   // 4096 x 4096
    const u16* B = vT + (size_t)b * 1536 * 4096;    // 1536 x 4096 (N x K)
    int L = xcd_swz(blockIdx.x, 96);
    int m0 = (L / 6) * 256, n0 = (L % 6) * 256;
    gemm8(A, 4096, B, 4096, 64, m0, n0, lds, acc);

    EPI_COORDS();
    #pragma unroll
    for (int mi = 0; mi < 8; ++mi)
        #pragma unroll
        for (int nj = 0; nj < 4; ++nj)
            #pragma unroll
            for (int rr = 0; rr < 4; ++rr) {
                int m = m0 + wr * 128 + mi * 16 + lq * 4 + rr;
                int n = n0 + wc * 64 + nj * 16 + lr;
                size_t idx = (size_t)(b * 4096 + m) * 3328 + n;
                h[idx] = f2bf(bf2f(h[idx]) * acc[mi][nj][rr]);
            }
}

// ---------------------------------------------------------------------------
// GEMM3: o = (u*z) @ Wo + bo -> f32 out  (A = h's u-region, lda 3328)
// ---------------------------------------------------------------------------
__global__ __launch_bounds__(512, 2) void k_out(
    const u16* __restrict__ h, const u16* __restrict__ WobT,
    const float* __restrict__ bo, float* __restrict__ out)
{
    __shared__ __align__(16) u16 lds[8 * 8192];
    f32x4 acc[8][4] = {};
    int L = xcd_swz(blockIdx.x, 192);
    int m0 = (L / 3) * 256, n0 = (L % 3) * 256;
    gemm8(h, 3328, WobT, 1536, 24, m0, n0, lds, acc);

    EPI_COORDS();
    #pragma unroll
    for (int mi = 0; mi < 8; ++mi)
        #pragma unroll
        for (int nj = 0; nj < 4; ++nj)
            #pragma unroll
            for (int rr = 0; rr < 4; ++rr) {
                int m = m0 + wr * 128 + mi * 16 + lq * 4 + rr;
                int n = n0 + wc * 64 + nj * 16 + lr;
                out[(size_t)m * 768 + n] = acc[mi][nj][rr] + bo[n];
            }
}

// ---------------------------------------------------------------------------
extern "C" void kernel_launch(void* const* d_in, const int* in_sizes, int n_in,
                              void* d_out, int out_size, void* d_ws, size_t ws_size,
                              hipStream_t stream)
{
    const float* x  = (const float*)d_in[0];
    const float* Wi = (const float*)d_in[1];
    const float* bi = (const float*)d_in[2];
    const float* gq = (const float*)d_in[3];
    const float* bq = (const float*)d_in[4];
    const float* gk = (const float*)d_in[5];
    const float* bk = (const float*)d_in[6];
    const float* Wo = (const float*)d_in[7];
    const float* bo = (const float*)d_in[8];
    float* out = (float*)d_out;

    char* ws = (char*)d_ws;
    size_t off = 0;
    auto alloc = [&](size_t bytes) -> void* {
        void* p = ws + off;
        off += (bytes + 255) & ~(size_t)255;
        return p;
    };
    u16* xb   = (u16*)alloc((size_t)16384 * 768 * 2);
    u16* WibT = (u16*)alloc((size_t)3328 * 768 * 2);     // padded N: 3200 -> 3328
    u16* WobT = (u16*)alloc((size_t)768 * 1536 * 2);
    u16* h    = (u16*)alloc((size_t)16384 * 3328 * 2);   // raw GEMM1 out; u/uz in place
    u16* vT   = (u16*)alloc((size_t)4 * 1536 * 4096 * 2);
    u16* q    = (u16*)alloc((size_t)16384 * 128 * 2);
    u16* k    = (u16*)alloc((size_t)16384 * 128 * 2);
    u16* P    = (u16*)alloc((size_t)2 * 4096 * 4096 * 2); // 2-batch chunk

    k_cast_x<<<dim3(12288), dim3(256), 0, stream>>>(x, xb);
    k_transpose_w<<<dim3(3328 / 32, 768 / 32), dim3(32, 8), 0, stream>>>(Wi, WibT, 768, 3200);
    k_transpose_w<<<dim3(768 / 32, 1536 / 32), dim3(32, 8), 0, stream>>>(Wo, WobT, 1536, 768);

    k_gemm1<<<dim3(832), dim3(512), 0, stream>>>(xb, WibT, h);
    k_split<<<dim3(256, 50), dim3(256), 0, stream>>>(h, bi, gq, bq, gk, bk, vT, q, k);

    for (int b0 = 0; b0 < 4; b0 += 2) {
        k_scores<<<dim3(256, 2), dim3(512), 0, stream>>>(q, k, P, b0);
        k_zu<<<dim3(96, 2), dim3(512), 0, stream>>>(P, vT, h, b0);
    }

    k_out<<<dim3(192), dim3(512), 0, stream>>>(h, WobT, bo, out);
}